// Round 1
// baseline (323.065 us; speedup 1.0000x reference)
//
#include <hip/hip_runtime.h>

#define BATCH 256
#define SEQ   256
#define CDIM  384
#define HDIM  64

typedef __attribute__((ext_vector_type(8))) short bf16x8;
typedef __attribute__((ext_vector_type(4))) float f32x4;

__device__ __forceinline__ short f2bf(float f) {
  union { float f; unsigned u; } v; v.f = f;
  unsigned r = v.u + 0x7FFFu + ((v.u >> 16) & 1u);   // RNE
  return (short)(r >> 16);
}

// ---------------------------------------------------------------------------
// kernel 0: WT[n][kk] = W*[kk][n] as bf16.  n: 0-63 -> Wq cols, 64-127 -> Wk,
// 128-191 -> Wv.  Tiny (221K elems); strided reads hit L2.
// ---------------------------------------------------------------------------
__global__ void wtrans_kernel(const float* __restrict__ Wk, const float* __restrict__ Wq,
                              const float* __restrict__ Wv, unsigned short* __restrict__ WT) {
  int gid = blockIdx.x * 256 + threadIdx.x;
  if (gid >= 192 * CDIM) return;
  int n = gid / CDIM, kk = gid - n * CDIM;
  const float* W = (n < 64) ? Wq : (n < 128) ? Wk : Wv;
  WT[gid] = (unsigned short)f2bf(W[kk * HDIM + (n & 63)]);
}

// ---------------------------------------------------------------------------
// kernel 1: q,k,v = x @ [Wq|Wk|Wv]  -> bf16 in ws.
// 256 blocks (1 batch each, 256 rows), 512 threads (8 waves).
// WT staged in LDS once (padded 384->392: row stride 196 dwords == 4 mod 32,
// so b_frag ds_read_b128 is 2 lanes/bank = conflict-free).
// ---------------------------------------------------------------------------
__global__ __launch_bounds__(512) void proj_kernel(
    const float* __restrict__ x, const unsigned short* __restrict__ WT,
    unsigned short* __restrict__ qws, unsigned short* __restrict__ kws,
    unsigned short* __restrict__ vws) {
  __shared__ unsigned short wt[192][392];   // 150528 B
  const int tid = threadIdx.x, bid = blockIdx.x;

  for (int c = tid; c < 192 * 48; c += 512) {            // 48 chunks of 8 bf16 per row
    int n = c / 48, kc = c - n * 48;
    *(uint4*)&wt[n][kc * 8] = *(const uint4*)&WT[n * CDIM + kc * 8];
  }
  __syncthreads();

  const int w = tid >> 6, lane = tid & 63;
  const int ln15 = lane & 15, quad = lane >> 4;

  for (int mi = 0; mi < 2; ++mi) {
    const int mt = w + 8 * mi;                           // 16-row M-tile
    f32x4 acc[12];
    #pragma unroll
    for (int nt = 0; nt < 12; ++nt) acc[nt] = (f32x4){0.f, 0.f, 0.f, 0.f};

    for (int ks = 0; ks < 12; ++ks) {                    // K = 384 = 12 x 32
      const float* ap = x + (size_t)(bid * 256 + mt * 16 + ln15) * CDIM + ks * 32 + quad * 8;
      float4 A0 = *(const float4*)ap;
      float4 A1 = *(const float4*)(ap + 4);
      bf16x8 af;
      af[0] = f2bf(A0.x); af[1] = f2bf(A0.y); af[2] = f2bf(A0.z); af[3] = f2bf(A0.w);
      af[4] = f2bf(A1.x); af[5] = f2bf(A1.y); af[6] = f2bf(A1.z); af[7] = f2bf(A1.w);
      #pragma unroll
      for (int nt = 0; nt < 12; ++nt) {
        bf16x8 bf = *(const bf16x8*)&wt[nt * 16 + ln15][ks * 32 + quad * 8];
        acc[nt] = __builtin_amdgcn_mfma_f32_16x16x32_bf16(af, bf, acc[nt], 0, 0, 0);
      }
    }
    // C/D layout: row=(lane>>4)*4+i, col=lane&15  (m89/m91 verified)
    #pragma unroll
    for (int nt = 0; nt < 12; ++nt) {
      unsigned short* dst = (nt < 4) ? qws : (nt < 8) ? kws : vws;
      int colb = (nt & 3) * 16 + ln15;
      #pragma unroll
      for (int i = 0; i < 4; ++i) {
        int t = mt * 16 + quad * 4 + i;
        dst[(size_t)(bid * 256 + t) * HDIM + colb] = (unsigned short)f2bf(acc[nt][i]);
      }
    }
  }
}

// ---------------------------------------------------------------------------
// kernel 2: causal attention per batch.  1 block = 1 batch, 512 threads.
// k [256][72], vT [64][264], per-wave P [16][264] in LDS (strides 36/132/132
// dwords == 4 mod 32 -> 2 lanes/bank = free).  Full score row in registers,
// quad-local shfl softmax, P via LDS for C->A layout transform.
// Wave pairing mt = {w, 15-w} balances causal work (18 n-tiles per wave).
// ---------------------------------------------------------------------------
__global__ __launch_bounds__(512) void attn_kernel(
    const unsigned short* __restrict__ qws, const unsigned short* __restrict__ kws,
    const unsigned short* __restrict__ vws, float* __restrict__ out) {
  __shared__ unsigned short kl[256][72];      // 36864 B
  __shared__ unsigned short vt[64][264];      // 33792 B
  __shared__ unsigned short pl[8][16][264];   // 67584 B   (total 138240 B)
  const int tid = threadIdx.x, b = blockIdx.x;

  for (int c = tid; c < 2048; c += 512) {     // k: [256][64] bf16, 16B chunks
    int t = c >> 3, hc = c & 7;
    *(uint4*)&kl[t][hc * 8] = *(const uint4*)&kws[(size_t)(b * 256 + t) * HDIM + hc * 8];
  }
  {                                           // v transposed: vt[h][t]
    int t = tid >> 1, hh = (tid & 1) * 32;
    const unsigned short* src = &vws[(size_t)(b * 256 + t) * HDIM + hh];
    uint4 t4[4];
    t4[0] = *(const uint4*)(src);
    t4[1] = *(const uint4*)(src + 8);
    t4[2] = *(const uint4*)(src + 16);
    t4[3] = *(const uint4*)(src + 24);
    const unsigned short* tv = (const unsigned short*)t4;
    #pragma unroll
    for (int j = 0; j < 32; ++j) vt[hh + j][t] = tv[j];
  }
  __syncthreads();

  const int w = tid >> 6, lane = tid & 63;
  const int ln15 = lane & 15, quad = lane >> 4;

  for (int mi = 0; mi < 2; ++mi) {
    const int mt = (mi == 0) ? w : (15 - w);
    const int t0 = mt * 16;
    const int NT = (mt | 1) + 1;              // even # of 16-wide s-tiles (32-aligned for PV)

    bf16x8 aq[2];
    #pragma unroll
    for (int ks = 0; ks < 2; ++ks)
      aq[ks] = *(const bf16x8*)&qws[(size_t)(b * 256 + t0 + ln15) * HDIM + ks * 32 + quad * 8];

    float sv[16][4];
    #pragma unroll
    for (int nt = 0; nt < 16; ++nt) {
      if (nt < NT) {
        f32x4 acc = (f32x4){0.f, 0.f, 0.f, 0.f};
        #pragma unroll
        for (int ks = 0; ks < 2; ++ks) {
          bf16x8 bf = *(const bf16x8*)&kl[nt * 16 + ln15][ks * 32 + quad * 8];
          acc = __builtin_amdgcn_mfma_f32_16x16x32_bf16(aq[ks], bf, acc, 0, 0, 0);
        }
        int colg = nt * 16 + ln15;
        #pragma unroll
        for (int i = 0; i < 4; ++i) {
          int rowg = t0 + quad * 4 + i;
          sv[nt][i] = (colg <= rowg) ? acc[i] * 0.125f : -3.0e38f;  // 1/sqrt(64)
        }
      }
    }
    float mx[4] = {-3.0e38f, -3.0e38f, -3.0e38f, -3.0e38f};
    #pragma unroll
    for (int nt = 0; nt < 16; ++nt)
      if (nt < NT) {
        #pragma unroll
        for (int i = 0; i < 4; ++i) mx[i] = fmaxf(mx[i], sv[nt][i]);
      }
    #pragma unroll
    for (int i = 0; i < 4; ++i) {             // reduce across the 16-lane quad group
      mx[i] = fmaxf(mx[i], __shfl_xor(mx[i], 8, 64));
      mx[i] = fmaxf(mx[i], __shfl_xor(mx[i], 4, 64));
      mx[i] = fmaxf(mx[i], __shfl_xor(mx[i], 2, 64));
      mx[i] = fmaxf(mx[i], __shfl_xor(mx[i], 1, 64));
    }
    float sm[4] = {0.f, 0.f, 0.f, 0.f};
    #pragma unroll
    for (int nt = 0; nt < 16; ++nt)
      if (nt < NT) {
        #pragma unroll
        for (int i = 0; i < 4; ++i) {
          float e = __expf(sv[nt][i] - mx[i]);
          sv[nt][i] = e;
          sm[i] += e;
        }
      }
    #pragma unroll
    for (int i = 0; i < 4; ++i) {
      sm[i] += __shfl_xor(sm[i], 8, 64);
      sm[i] += __shfl_xor(sm[i], 4, 64);
      sm[i] += __shfl_xor(sm[i], 2, 64);
      sm[i] += __shfl_xor(sm[i], 1, 64);
    }
    float inv[4];
    #pragma unroll
    for (int i = 0; i < 4; ++i) inv[i] = 1.0f / sm[i];

    #pragma unroll
    for (int nt = 0; nt < 16; ++nt)           // P (normalized) -> LDS, A-layout rows
      if (nt < NT) {
        int cl = nt * 16 + ln15;
        #pragma unroll
        for (int i = 0; i < 4; ++i)
          pl[w][quad * 4 + i][cl] = (unsigned short)f2bf(sv[nt][i] * inv[i]);
      }

    #pragma unroll
    for (int ont = 0; ont < 4; ++ont) {       // out = P @ V
      f32x4 o = (f32x4){0.f, 0.f, 0.f, 0.f};
      #pragma unroll
      for (int ks = 0; ks < 8; ++ks) {
        if (ks * 2 < NT) {
          bf16x8 pa = *(const bf16x8*)&pl[w][ln15][ks * 32 + quad * 8];
          bf16x8 vb = *(const bf16x8*)&vt[ont * 16 + ln15][ks * 32 + quad * 8];
          o = __builtin_amdgcn_mfma_f32_16x16x32_bf16(pa, vb, o, 0, 0, 0);
        }
      }
      int h = ont * 16 + ln15;
      #pragma unroll
      for (int i = 0; i < 4; ++i)
        out[(size_t)(b * 256 + t0 + quad * 4 + i) * HDIM + h] = o[i];
    }
  }
}

// ---------------------------------------------------------------------------
// ws layout: WT bf16 @0 (147456 B), then q/k/v bf16 (8 MB each) @256 KB.
// Needs ws_size >= 25.5 MB.
// ---------------------------------------------------------------------------
extern "C" void kernel_launch(void* const* d_in, const int* in_sizes, int n_in,
                              void* d_out, int out_size, void* d_ws, size_t ws_size,
                              hipStream_t stream) {
  const float* x  = (const float*)d_in[0];
  const float* Wk = (const float*)d_in[1];
  const float* Wq = (const float*)d_in[2];
  const float* Wv = (const float*)d_in[3];
  float* out = (float*)d_out;

  char* ws = (char*)d_ws;
  unsigned short* WT  = (unsigned short*)ws;
  unsigned short* qws = (unsigned short*)(ws + 262144);
  unsigned short* kws = qws + (size_t)BATCH * SEQ * HDIM;
  unsigned short* vws = kws + (size_t)BATCH * SEQ * HDIM;

  wtrans_kernel<<<(192 * CDIM + 255) / 256, 256, 0, stream>>>(Wk, Wq, Wv, WT);
  proj_kernel<<<BATCH, 512, 0, stream>>>(x, WT, qws, kws, vws);
  attn_kernel<<<BATCH, 512, 0, stream>>>(qws, kws, vws, out);
}

// Round 2
// 256.040 us; speedup vs baseline: 1.2618x; 1.2618x over previous
//
#include <hip/hip_runtime.h>

#define BATCH 256
#define SEQ   256
#define CDIM  384
#define HDIM  64

typedef __attribute__((ext_vector_type(8))) short bf16x8;
typedef __attribute__((ext_vector_type(4))) float f32x4;

__device__ __forceinline__ unsigned f2bf(float f) {
  union { float f; unsigned u; } v; v.f = f;
  unsigned r = v.u + 0x7FFFu + ((v.u >> 16) & 1u);   // RNE
  return r >> 16;
}

// ---------------------------------------------------------------------------
// kernel 0: WT[n][kk] = W*[kk][n] as bf16.  n: 0-63 -> Wq cols, 64-127 -> Wk,
// 128-191 -> Wv.  Tiny; strided reads hit L2.
// ---------------------------------------------------------------------------
__global__ void wtrans_kernel(const float* __restrict__ Wk, const float* __restrict__ Wq,
                              const float* __restrict__ Wv, unsigned short* __restrict__ WT) {
  int gid = blockIdx.x * 256 + threadIdx.x;
  if (gid >= 192 * CDIM) return;
  int n = gid / CDIM, kk = gid - n * CDIM;
  const float* W = (n < 64) ? Wq : (n < 128) ? Wk : Wv;
  WT[gid] = (unsigned short)f2bf(W[kk * HDIM + (n & 63)]);
}

// ---------------------------------------------------------------------------
// kernel 1: q,k,v = x @ [Wq|Wk|Wv].  1024 blocks x 256 thr, wave = 16 t-rows.
// OPERAND SWAP: A = WT (m=h), B = x (n=t)  ->  C col = t, row = h: each lane
// holds 4 consecutive h for one t -> 8-byte packed stores, no write amp.
// WT read from global (147 KB, L1/L2-resident, shared by all waves) - no LDS
// for the GEMM; small vtile LDS transposes v -> vT[b][h][t] for attn's
// PV B-operand.
// ---------------------------------------------------------------------------
__global__ __launch_bounds__(256, 4) void proj_kernel(
    const float* __restrict__ x, const unsigned short* __restrict__ WT,
    unsigned short* __restrict__ qws, unsigned short* __restrict__ kws,
    unsigned short* __restrict__ vT) {
  __shared__ unsigned short vtile[64][72];   // 9216 B; stride 36 dw (=4 mod 32)
  const int tid = threadIdx.x, bid = blockIdx.x;
  const int w = tid >> 6, lane = tid & 63;
  const int ln15 = lane & 15, quad = lane >> 4;
  const int t0 = bid * 64 + w * 16;          // global t-row base for this wave

  f32x4 acc[12];
  #pragma unroll
  for (int nt = 0; nt < 12; ++nt) acc[nt] = (f32x4){0.f, 0.f, 0.f, 0.f};

  for (int ks = 0; ks < 12; ++ks) {          // K = 384 = 12 x 32
    const float* ap = x + (size_t)(t0 + ln15) * CDIM + ks * 32 + quad * 8;
    float4 A0 = *(const float4*)ap;
    float4 A1 = *(const float4*)(ap + 4);
    bf16x8 bx;
    bx[0] = (short)f2bf(A0.x); bx[1] = (short)f2bf(A0.y);
    bx[2] = (short)f2bf(A0.z); bx[3] = (short)f2bf(A0.w);
    bx[4] = (short)f2bf(A1.x); bx[5] = (short)f2bf(A1.y);
    bx[6] = (short)f2bf(A1.z); bx[7] = (short)f2bf(A1.w);
    #pragma unroll
    for (int nt = 0; nt < 12; ++nt) {
      bf16x8 aw = *(const bf16x8*)&WT[(size_t)(nt * 16 + ln15) * CDIM + ks * 32 + quad * 8];
      acc[nt] = __builtin_amdgcn_mfma_f32_16x16x32_bf16(aw, bx, acc[nt], 0, 0, 0);
    }
  }

  // epilogue: lane owns qkv[t0+ln15][nt*16 + quad*4 .. +3]
  #pragma unroll
  for (int nt = 0; nt < 12; ++nt) {
    unsigned p0 = f2bf(acc[nt][0]) | (f2bf(acc[nt][1]) << 16);
    unsigned p1 = f2bf(acc[nt][2]) | (f2bf(acc[nt][3]) << 16);
    int hl = (nt & 3) * 16 + quad * 4;
    if (nt < 8) {
      unsigned short* dst = (nt < 4) ? qws : kws;
      uint2* p = (uint2*)&dst[(size_t)(t0 + ln15) * HDIM + hl];
      *p = (uint2){p0, p1};
    } else {
      int tl = w * 16 + ln15;                // block-local t (0..63)
      vtile[hl + 0][tl] = (unsigned short)(p0 & 0xFFFF);
      vtile[hl + 1][tl] = (unsigned short)(p0 >> 16);
      vtile[hl + 2][tl] = (unsigned short)(p1 & 0xFFFF);
      vtile[hl + 3][tl] = (unsigned short)(p1 >> 16);
    }
  }
  __syncthreads();
  // vT store: 64 h-rows x 64 t-cols; thread -> (h = tid>>2, 16-t chunk c)
  {
    int h = tid >> 2, c = tid & 3;
    uint4 d0 = *(const uint4*)&vtile[h][c * 16];
    uint4 d1 = *(const uint4*)&vtile[h][c * 16 + 8];
    unsigned short* dst = &vT[((size_t)(bid >> 2) * 64 + h) * SEQ + (bid & 3) * 64 + c * 16];
    *(uint4*)dst = d0;
    *(uint4*)(dst + 8) = d1;
  }
}

// ---------------------------------------------------------------------------
// kernel 2: causal attention.  1 block = 1 batch, 512 thr, 2 blocks/CU.
// No staging, no barriers: q/k/vT fragments read straight from L2-resident
// ws; only LDS is the per-wave P C->A-layout transform buffer.
// Wave pairing mt = {w, 15-w} balances causal work.
// ---------------------------------------------------------------------------
__global__ __launch_bounds__(512, 4) void attn_kernel(
    const unsigned short* __restrict__ qws, const unsigned short* __restrict__ kws,
    const unsigned short* __restrict__ vT, float* __restrict__ out) {
  __shared__ unsigned short pl[8][16][264];   // 67584 B; stride 132 dw (=4 mod 32)
  const int tid = threadIdx.x, b = blockIdx.x;
  const int w = tid >> 6, lane = tid & 63;
  const int ln15 = lane & 15, quad = lane >> 4;

  for (int mi = 0; mi < 2; ++mi) {
    const int mt = (mi == 0) ? w : (15 - w);
    const int t0 = mt * 16;
    const int NT = (mt | 1) + 1;              // even # of 16-wide s-tiles

    bf16x8 aq[2];
    #pragma unroll
    for (int ks = 0; ks < 2; ++ks)
      aq[ks] = *(const bf16x8*)&qws[(size_t)(b * 256 + t0 + ln15) * HDIM + ks * 32 + quad * 8];

    float sv[16][4];
    #pragma unroll
    for (int nt = 0; nt < 16; ++nt) {
      if (nt < NT) {
        f32x4 acc = (f32x4){0.f, 0.f, 0.f, 0.f};
        #pragma unroll
        for (int ks = 0; ks < 2; ++ks) {
          bf16x8 bf = *(const bf16x8*)&kws[(size_t)(b * 256 + nt * 16 + ln15) * HDIM + ks * 32 + quad * 8];
          acc = __builtin_amdgcn_mfma_f32_16x16x32_bf16(aq[ks], bf, acc, 0, 0, 0);
        }
        int colg = nt * 16 + ln15;
        #pragma unroll
        for (int i = 0; i < 4; ++i) {
          int rowg = t0 + quad * 4 + i;
          sv[nt][i] = (colg <= rowg) ? acc[i] * 0.125f : -3.0e38f;  // 1/sqrt(64)
        }
      }
    }
    float mx[4] = {-3.0e38f, -3.0e38f, -3.0e38f, -3.0e38f};
    #pragma unroll
    for (int nt = 0; nt < 16; ++nt)
      if (nt < NT) {
        #pragma unroll
        for (int i = 0; i < 4; ++i) mx[i] = fmaxf(mx[i], sv[nt][i]);
      }
    #pragma unroll
    for (int i = 0; i < 4; ++i) {             // reduce across the 16-lane group
      mx[i] = fmaxf(mx[i], __shfl_xor(mx[i], 8, 64));
      mx[i] = fmaxf(mx[i], __shfl_xor(mx[i], 4, 64));
      mx[i] = fmaxf(mx[i], __shfl_xor(mx[i], 2, 64));
      mx[i] = fmaxf(mx[i], __shfl_xor(mx[i], 1, 64));
    }
    float sm[4] = {0.f, 0.f, 0.f, 0.f};
    #pragma unroll
    for (int nt = 0; nt < 16; ++nt)
      if (nt < NT) {
        #pragma unroll
        for (int i = 0; i < 4; ++i) {
          float e = __expf(sv[nt][i] - mx[i]);
          sv[nt][i] = e;
          sm[i] += e;
        }
      }
    #pragma unroll
    for (int i = 0; i < 4; ++i) {
      sm[i] += __shfl_xor(sm[i], 8, 64);
      sm[i] += __shfl_xor(sm[i], 4, 64);
      sm[i] += __shfl_xor(sm[i], 2, 64);
      sm[i] += __shfl_xor(sm[i], 1, 64);
    }
    float inv[4];
    #pragma unroll
    for (int i = 0; i < 4; ++i) inv[i] = 1.0f / sm[i];

    #pragma unroll
    for (int nt = 0; nt < 16; ++nt)           // P (normalized) -> LDS, A-layout rows
      if (nt < NT) {
        int cl = nt * 16 + ln15;
        #pragma unroll
        for (int i = 0; i < 4; ++i)
          pl[w][quad * 4 + i][cl] = (unsigned short)f2bf(sv[nt][i] * inv[i]);
      }

    #pragma unroll
    for (int ont = 0; ont < 4; ++ont) {       // out = P @ V   (B-frags from global vT)
      f32x4 o = (f32x4){0.f, 0.f, 0.f, 0.f};
      #pragma unroll
      for (int ks = 0; ks < 8; ++ks) {
        if (ks * 2 < NT) {
          bf16x8 pa = *(const bf16x8*)&pl[w][ln15][ks * 32 + quad * 8];
          bf16x8 vb = *(const bf16x8*)&vT[(size_t)(b * 64 + ont * 16 + ln15) * SEQ + ks * 32 + quad * 8];
          o = __builtin_amdgcn_mfma_f32_16x16x32_bf16(pa, vb, o, 0, 0, 0);
        }
      }
      int h = ont * 16 + ln15;
      #pragma unroll
      for (int i = 0; i < 4; ++i)
        out[(size_t)(b * 256 + t0 + quad * 4 + i) * HDIM + h] = o[i];
    }
  }
}

// ---------------------------------------------------------------------------
// ws layout: WT bf16 @0 (147456 B, pad to 256 KB), then q/k bf16 row-major and
// vT bf16 [B][H][T] (8 MB each).  Needs ws_size >= 24.5 MB.
// ---------------------------------------------------------------------------
extern "C" void kernel_launch(void* const* d_in, const int* in_sizes, int n_in,
                              void* d_out, int out_size, void* d_ws, size_t ws_size,
                              hipStream_t stream) {
  const float* x  = (const float*)d_in[0];
  const float* Wk = (const float*)d_in[1];
  const float* Wq = (const float*)d_in[2];
  const float* Wv = (const float*)d_in[3];
  float* out = (float*)d_out;

  char* ws = (char*)d_ws;
  unsigned short* WT  = (unsigned short*)ws;
  unsigned short* qws = (unsigned short*)(ws + 262144);
  unsigned short* kws = qws + (size_t)BATCH * SEQ * HDIM;
  unsigned short* vT  = kws + (size_t)BATCH * SEQ * HDIM;

  wtrans_kernel<<<(192 * CDIM + 255) / 256, 256, 0, stream>>>(Wk, Wq, Wv, WT);
  proj_kernel<<<1024, 256, 0, stream>>>(x, WT, qws, kws, vT);
  attn_kernel<<<BATCH, 512, 0, stream>>>(qws, kws, vT, out);
}

// Round 3
// 236.330 us; speedup vs baseline: 1.3670x; 1.0834x over previous
//
#include <hip/hip_runtime.h>

#define BATCH 256
#define SEQ   256
#define CDIM  384
#define HDIM  64

typedef __attribute__((ext_vector_type(8))) short bf16x8;
typedef __attribute__((ext_vector_type(4))) float f32x4;

__device__ __forceinline__ unsigned f2bf(float f) {
  union { float f; unsigned u; } v; v.f = f;
  unsigned r = v.u + 0x7FFFu + ((v.u >> 16) & 1u);   // RNE
  return r >> 16;
}

// ---------------------------------------------------------------------------
// kernel 0: WT[n][kk] = W*[kk][n] as bf16.  n: 0-63 -> Wq, 64-127 -> Wk,
// 128-191 -> Wv.  Tiny; L2-resident.
// ---------------------------------------------------------------------------
__global__ void wtrans_kernel(const float* __restrict__ Wk, const float* __restrict__ Wq,
                              const float* __restrict__ Wv, unsigned short* __restrict__ WT) {
  int gid = blockIdx.x * 256 + threadIdx.x;
  if (gid >= 192 * CDIM) return;
  int n = gid / CDIM, kk = gid - n * CDIM;
  const float* W = (n < 64) ? Wq : (n < 128) ? Wk : Wv;
  WT[gid] = (unsigned short)f2bf(W[kk * HDIM + (n & 63)]);
}

// ---------------------------------------------------------------------------
// kernel 1: q,k,v = x @ [Wq|Wk|Wv].  1024 blocks x 256 thr, wave = 16 t-rows.
// A = WT (m=h), B = x (n=t): C-layout gives 4 consecutive h per lane -> packed
// 8B stores.  MLP fix: per K-step, issue x loads then ALL 12 WT b-frag loads
// into registers before any use -> 14 loads in flight, one latency stall per
// ks instead of 14 serialized.
// ---------------------------------------------------------------------------
__global__ __launch_bounds__(256, 4) void proj_kernel(
    const float* __restrict__ x, const unsigned short* __restrict__ WT,
    unsigned short* __restrict__ qws, unsigned short* __restrict__ kws,
    unsigned short* __restrict__ vT) {
  __shared__ unsigned short vtile[64][72];   // 9216 B; stride 36 dw
  const int tid = threadIdx.x, bid = blockIdx.x;
  const int w = tid >> 6, lane = tid & 63;
  const int ln15 = lane & 15, quad = lane >> 4;
  const int t0 = bid * 64 + w * 16;

  f32x4 acc[12];
  #pragma unroll
  for (int nt = 0; nt < 12; ++nt) acc[nt] = (f32x4){0.f, 0.f, 0.f, 0.f};

  const float* xrow = x + (size_t)(t0 + ln15) * CDIM + quad * 8;
  const unsigned short* wbase = WT + (size_t)ln15 * CDIM + quad * 8;

  for (int ks = 0; ks < 12; ++ks) {
    float4 A0 = *(const float4*)(xrow + ks * 32);       // issue x first
    float4 A1 = *(const float4*)(xrow + ks * 32 + 4);
    bf16x8 aw[12];                                      // then all 12 WT frags
    #pragma unroll
    for (int nt = 0; nt < 12; ++nt)
      aw[nt] = *(const bf16x8*)(wbase + (size_t)nt * 16 * CDIM + ks * 32);
    bf16x8 bx;
    bx[0] = (short)f2bf(A0.x); bx[1] = (short)f2bf(A0.y);
    bx[2] = (short)f2bf(A0.z); bx[3] = (short)f2bf(A0.w);
    bx[4] = (short)f2bf(A1.x); bx[5] = (short)f2bf(A1.y);
    bx[6] = (short)f2bf(A1.z); bx[7] = (short)f2bf(A1.w);
    #pragma unroll
    for (int nt = 0; nt < 12; ++nt)
      acc[nt] = __builtin_amdgcn_mfma_f32_16x16x32_bf16(aw[nt], bx, acc[nt], 0, 0, 0);
  }

  // epilogue: lane owns qkv[t0+ln15][nt*16 + quad*4 .. +3]
  #pragma unroll
  for (int nt = 0; nt < 12; ++nt) {
    unsigned p0 = f2bf(acc[nt][0]) | (f2bf(acc[nt][1]) << 16);
    unsigned p1 = f2bf(acc[nt][2]) | (f2bf(acc[nt][3]) << 16);
    int hl = (nt & 3) * 16 + quad * 4;
    if (nt < 8) {
      unsigned short* dst = (nt < 4) ? qws : kws;
      uint2* p = (uint2*)&dst[(size_t)(t0 + ln15) * HDIM + hl];
      *p = (uint2){p0, p1};
    } else {
      int tl = w * 16 + ln15;                // block-local t (0..63)
      vtile[hl + 0][tl] = (unsigned short)(p0 & 0xFFFF);
      vtile[hl + 1][tl] = (unsigned short)(p0 >> 16);
      vtile[hl + 2][tl] = (unsigned short)(p1 & 0xFFFF);
      vtile[hl + 3][tl] = (unsigned short)(p1 >> 16);
    }
  }
  __syncthreads();
  {
    int h = tid >> 2, c = tid & 3;
    uint4 d0 = *(const uint4*)&vtile[h][c * 16];
    uint4 d1 = *(const uint4*)&vtile[h][c * 16 + 8];
    unsigned short* dst = &vT[((size_t)(bid >> 2) * 64 + h) * SEQ + (bid & 3) * 64 + c * 16];
    *(uint4*)dst = d0;
    *(uint4*)(dst + 8) = d1;
  }
}

// ---------------------------------------------------------------------------
// kernel 2: causal attention.  1 block = 1 batch, 512 thr.
// k and vT staged in LDS via coalesced uint4 copies (vT already transposed by
// proj -> straight copy).  PV runs in 32-wide K chunks through a per-wave
// 16x32 P buffer (wave-private: no barriers after the initial staging sync).
// LDS total 80.9 KB -> 2 blocks/CU.  Wave pairing mt={w,15-w} balances causal
// work.  All MFMA operands come from LDS (short latency, fine-grained lgkmcnt).
// ---------------------------------------------------------------------------
__global__ __launch_bounds__(512, 4) void attn_kernel(
    const unsigned short* __restrict__ qws, const unsigned short* __restrict__ kws,
    const unsigned short* __restrict__ vT, float* __restrict__ out) {
  __shared__ unsigned short kl[256][72];     // 36864 B; stride 36 dw (=4 mod 32)
  __shared__ unsigned short vt[64][264];     // 33792 B; stride 132 dw (=4 mod 32)
  __shared__ unsigned short pl[8][16][40];   // 10240 B; stride 20 dw (even spread)
  const int tid = threadIdx.x, b = blockIdx.x;
  const int w = tid >> 6, lane = tid & 63;
  const int ln15 = lane & 15, quad = lane >> 4;

  for (int c = tid; c < 2048; c += 512) {    // k: 256x64 bf16, 16B chunks
    int t = c >> 3, hc = c & 7;
    *(uint4*)&kl[t][hc * 8] = *(const uint4*)&kws[(size_t)(b * 256 + t) * HDIM + hc * 8];
  }
  for (int c = tid; c < 2048; c += 512) {    // vT[b]: 64x256 bf16, straight copy
    int h = c >> 5, tc = c & 31;
    *(uint4*)&vt[h][tc * 8] = *(const uint4*)&vT[(size_t)(b * 64 + h) * SEQ + tc * 8];
  }
  __syncthreads();

  for (int mi = 0; mi < 2; ++mi) {
    const int mt = (mi == 0) ? w : (15 - w);
    const int t0 = mt * 16;
    const int NT = (mt | 1) + 1;             // even # of 16-wide s-tiles

    bf16x8 aq[2];
    #pragma unroll
    for (int ks = 0; ks < 2; ++ks)
      aq[ks] = *(const bf16x8*)&qws[(size_t)(b * 256 + t0 + ln15) * HDIM + ks * 32 + quad * 8];

    float sv[16][4];
    #pragma unroll
    for (int nt = 0; nt < 16; ++nt) {
      if (nt < NT) {
        f32x4 acc = (f32x4){0.f, 0.f, 0.f, 0.f};
        #pragma unroll
        for (int ks = 0; ks < 2; ++ks) {
          bf16x8 bf = *(const bf16x8*)&kl[nt * 16 + ln15][ks * 32 + quad * 8];
          acc = __builtin_amdgcn_mfma_f32_16x16x32_bf16(aq[ks], bf, acc, 0, 0, 0);
        }
        int colg = nt * 16 + ln15;
        #pragma unroll
        for (int i = 0; i < 4; ++i) {
          int rowg = t0 + quad * 4 + i;
          sv[nt][i] = (colg <= rowg) ? acc[i] * 0.125f : -3.0e38f;  // 1/sqrt(64)
        }
      }
    }
    float mx[4] = {-3.0e38f, -3.0e38f, -3.0e38f, -3.0e38f};
    #pragma unroll
    for (int nt = 0; nt < 16; ++nt)
      if (nt < NT) {
        #pragma unroll
        for (int i = 0; i < 4; ++i) mx[i] = fmaxf(mx[i], sv[nt][i]);
      }
    #pragma unroll
    for (int i = 0; i < 4; ++i) {            // reduce across the 16-lane group
      mx[i] = fmaxf(mx[i], __shfl_xor(mx[i], 8, 64));
      mx[i] = fmaxf(mx[i], __shfl_xor(mx[i], 4, 64));
      mx[i] = fmaxf(mx[i], __shfl_xor(mx[i], 2, 64));
      mx[i] = fmaxf(mx[i], __shfl_xor(mx[i], 1, 64));
    }
    float sm[4] = {0.f, 0.f, 0.f, 0.f};
    #pragma unroll
    for (int nt = 0; nt < 16; ++nt)
      if (nt < NT) {
        #pragma unroll
        for (int i = 0; i < 4; ++i) {
          float e = __expf(sv[nt][i] - mx[i]);
          sv[nt][i] = e;
          sm[i] += e;
        }
      }
    #pragma unroll
    for (int i = 0; i < 4; ++i) {
      sm[i] += __shfl_xor(sm[i], 8, 64);
      sm[i] += __shfl_xor(sm[i], 4, 64);
      sm[i] += __shfl_xor(sm[i], 2, 64);
      sm[i] += __shfl_xor(sm[i], 1, 64);
    }
    float inv[4];
    #pragma unroll
    for (int i = 0; i < 4; ++i) inv[i] = 1.0f / sm[i];

    // PV in 32-wide K chunks through the per-wave P buffer (no barriers:
    // wave-private; DS pipe is in-order so write(k+1) can't pass read(k)).
    f32x4 o[4];
    #pragma unroll
    for (int ont = 0; ont < 4; ++ont) o[ont] = (f32x4){0.f, 0.f, 0.f, 0.f};

    for (int kc = 0; kc < 8; ++kc) {
      if (kc * 2 < NT) {
        #pragma unroll
        for (int half = 0; half < 2; ++half) {
          int nt = kc * 2 + half;
          #pragma unroll
          for (int i = 0; i < 4; ++i)
            pl[w][quad * 4 + i][half * 16 + ln15] =
                (unsigned short)f2bf(sv[nt][i] * inv[i]);
        }
        bf16x8 pa = *(const bf16x8*)&pl[w][ln15][quad * 8];
        #pragma unroll
        for (int ont = 0; ont < 4; ++ont) {
          bf16x8 vb = *(const bf16x8*)&vt[ont * 16 + ln15][kc * 32 + quad * 8];
          o[ont] = __builtin_amdgcn_mfma_f32_16x16x32_bf16(pa, vb, o[ont], 0, 0, 0);
        }
      }
    }

    #pragma unroll
    for (int ont = 0; ont < 4; ++ont) {
      int h = ont * 16 + ln15;
      #pragma unroll
      for (int i = 0; i < 4; ++i)
        out[(size_t)(b * 256 + t0 + quad * 4 + i) * HDIM + h] = o[ont][i];
    }
  }
}

// ---------------------------------------------------------------------------
// ws layout: WT bf16 @0 (147456 B, pad to 256 KB), then q/k bf16 row-major and
// vT bf16 [B][H][T] (8 MB each).  Needs ws_size >= 24.5 MB.
// ---------------------------------------------------------------------------
extern "C" void kernel_launch(void* const* d_in, const int* in_sizes, int n_in,
                              void* d_out, int out_size, void* d_ws, size_t ws_size,
                              hipStream_t stream) {
  const float* x  = (const float*)d_in[0];
  const float* Wk = (const float*)d_in[1];
  const float* Wq = (const float*)d_in[2];
  const float* Wv = (const float*)d_in[3];
  float* out = (float*)d_out;

  char* ws = (char*)d_ws;
  unsigned short* WT  = (unsigned short*)ws;
  unsigned short* qws = (unsigned short*)(ws + 262144);
  unsigned short* kws = qws + (size_t)BATCH * SEQ * HDIM;
  unsigned short* vT  = kws + (size_t)BATCH * SEQ * HDIM;

  wtrans_kernel<<<(192 * CDIM + 255) / 256, 256, 0, stream>>>(Wk, Wq, Wv, WT);
  proj_kernel<<<1024, 256, 0, stream>>>(x, WT, qws, kws, vT);
  attn_kernel<<<BATCH, 512, 0, stream>>>(qws, kws, vT, out);
}